// Round 4
// baseline (3054.671 us; speedup 1.0000x reference)
//
#include <hip/hip_runtime.h>
#include <hip/hip_bf16.h>
#include <math.h>

#define VOCAB 50257
#define CTX 2048
#define DMODEL 1024
#define NHEAD 16
#define NLAYER 8
#define DHEAD 64
#define BATCH 2
#define SEQ 2048
#define NTOK (BATCH * SEQ)   // 4096

typedef __bf16 bf16x8 __attribute__((ext_vector_type(8)));
typedef float  f32x4  __attribute__((ext_vector_type(4)));
typedef unsigned short ushort4v __attribute__((ext_vector_type(4)));

__device__ inline void gl_lds16(const void* g, void* l) {
    __builtin_amdgcn_global_load_lds(
        (const __attribute__((address_space(1))) unsigned int*)g,
        (__attribute__((address_space(3))) unsigned int*)l, 16, 0, 0);
}

__device__ inline unsigned short f2bs(float v) {
    __hip_bfloat16 t = __float2bfloat16(v);
    return *(unsigned short*)&t;
}

// ---------------- embedding ----------------
__global__ void embed_kernel(const int* __restrict__ x,
                             const float* __restrict__ wte,
                             const float* __restrict__ wpe,
                             float* __restrict__ h) {
    int t = blockIdx.x;
    int s = t & (SEQ - 1);
    int tok = x[t];
    const float* pe = wpe + (long)s * DMODEL;
    const float* te = wte + (long)tok * DMODEL;
    float* ph = h + (long)t * DMODEL;
    for (int d = threadIdx.x; d < DMODEL; d += 256)
        ph[d] = te[d] + pe[d];
}

// ---------------- layernorm ----------------
__device__ inline float wave_sum(float v) {
    for (int off = 32; off; off >>= 1) v += __shfl_xor(v, off);
    return v;
}
__device__ inline void st_val(float* p, float v) { *p = v; }
__device__ inline void st_val(__hip_bfloat16* p, float v) { *p = __float2bfloat16(v); }

template<typename OT>
__global__ void ln_kernel(const float* __restrict__ in, OT* __restrict__ out,
                          const float* __restrict__ g, const float* __restrict__ b,
                          long row_stride) {
    int row = blockIdx.x;
    const float* px = in + (long)row * row_stride;
    OT* po = out + (long)row * DMODEL;
    int tid = threadIdx.x;
    int wid = tid >> 6, lane = tid & 63;

    float x[4];
    float s = 0.f;
    #pragma unroll
    for (int i = 0; i < 4; ++i) { x[i] = px[tid + i * 256]; s += x[i]; }
    s = wave_sum(s);
    __shared__ float red[4], red2[4];
    if (lane == 0) red[wid] = s;
    __syncthreads();
    float mean = (red[0] + red[1] + red[2] + red[3]) * (1.0f / DMODEL);

    float s2 = 0.f;
    #pragma unroll
    for (int i = 0; i < 4; ++i) { float d = x[i] - mean; s2 += d * d; }
    s2 = wave_sum(s2);
    if (lane == 0) red2[wid] = s2;
    __syncthreads();
    float var = (red2[0] + red2[1] + red2[2] + red2[3]) * (1.0f / DMODEL);
    float r = 1.0f / sqrtf(var + 1e-5f);
    #pragma unroll
    for (int i = 0; i < 4; ++i) {
        int d = tid + i * 256;
        st_val(po + d, (x[i] - mean) * r * g[d] + b[d]);
    }
}

// ------------- batched transpose+convert of all layer weights -------------
// arena per layer (ushort elems): qkvT@0 (3072x1024), projT@3145728 (1024x1024),
// fcT@4194304 (4096x1024), cpT@8388608 (1024x4096). layer stride 12582912.
#define LWOFF 12582912L
__global__ void convT_all(const float* __restrict__ wq, const float* __restrict__ wp,
                          const float* __restrict__ wf, const float* __restrict__ wc,
                          unsigned short* __restrict__ arena) {
    __shared__ float t[32][33];
    int bid = blockIdx.x;
    int l = bid / 12288, r = bid % 12288;
    const float* W; unsigned short* WT; int K, N, bx, by;
    if (r < 3072)      { W = wq + l * 3145728L; WT = arena + l * LWOFF;            K = 1024; N = 3072; bx = r % 96;  by = r / 96; }
    else if (r < 4096) { r -= 3072; W = wp + l * 1048576L; WT = arena + l * LWOFF + 3145728; K = 1024; N = 1024; bx = r % 32;  by = r / 32; }
    else if (r < 8192) { r -= 4096; W = wf + l * 4194304L; WT = arena + l * LWOFF + 4194304; K = 1024; N = 4096; bx = r % 128; by = r / 128; }
    else               { r -= 8192; W = wc + l * 4194304L; WT = arena + l * LWOFF + 8388608; K = 4096; N = 1024; bx = r % 32;  by = r / 32; }
    int n0 = bx * 32, k0 = by * 32;
    int tx = threadIdx.x & 31, ty = threadIdx.x >> 5;
    #pragma unroll
    for (int i = 0; i < 4; ++i)
        t[ty + i * 8][tx] = W[(long)(k0 + ty + i * 8) * N + n0 + tx];
    __syncthreads();
    #pragma unroll
    for (int i = 0; i < 4; ++i)
        WT[(long)(n0 + ty + i * 8) * K + k0 + tx] = f2bs(t[tx][ty + i * 8]);
}

// ---------------- 128^2 bf16 MFMA GEMM (EPI 1: f32 +bias+R) ----------------
template<int EPI>
__global__ __launch_bounds__(256)
void mm_mfma(const unsigned short* __restrict__ A,
             const unsigned short* __restrict__ BT,
             const float* __restrict__ bias, const float* __restrict__ R,
             void* __restrict__ Cout, int M, int N, int K) {
    __shared__ unsigned short As[128 * 32];
    __shared__ unsigned short Bs[128 * 32];
    const int tid = threadIdx.x;
    const int w = tid >> 6, lane = tid & 63;
    const int bm = blockIdx.y * 128, bn = blockIdx.x * 128;
    const int wr = (w >> 1) * 64, wc = (w & 1) * 64;

    f32x4 acc[4][4];
    #pragma unroll
    for (int m = 0; m < 4; ++m)
        #pragma unroll
        for (int n = 0; n < 4; ++n)
            acc[m][n] = (f32x4){0.f, 0.f, 0.f, 0.f};

    const int lrow = lane >> 2;
    const int lcol = (lane & 3) * 8;
    const unsigned short* gA = A + (long)(bm + w * 32 + lrow) * K + lcol;
    const unsigned short* gB = BT + (long)(bn + w * 32 + lrow) * K + lcol;
    unsigned short* lA = &As[(w * 32) * 32];
    unsigned short* lB = &Bs[(w * 32) * 32];

    for (int k0 = 0; k0 < K; k0 += 32) {
        gl_lds16(gA + k0,          lA);
        gl_lds16(gA + k0 + 16 * K, lA + 16 * 32);
        gl_lds16(gB + k0,          lB);
        gl_lds16(gB + k0 + 16 * K, lB + 16 * 32);
        __syncthreads();

        bf16x8 a[4], b[4];
        #pragma unroll
        for (int m = 0; m < 4; ++m)
            a[m] = *(const bf16x8*)&As[(wr + m * 16 + (lane & 15)) * 32 + (lane >> 4) * 8];
        #pragma unroll
        for (int n = 0; n < 4; ++n)
            b[n] = *(const bf16x8*)&Bs[(wc + n * 16 + (lane & 15)) * 32 + (lane >> 4) * 8];
        #pragma unroll
        for (int m = 0; m < 4; ++m)
            #pragma unroll
            for (int n = 0; n < 4; ++n)
                acc[m][n] = __builtin_amdgcn_mfma_f32_16x16x32_bf16(a[m], b[n], acc[m][n], 0, 0, 0);
        __syncthreads();
    }

    const int r0 = (lane >> 4) * 4, cc = lane & 15;
    #pragma unroll
    for (int n = 0; n < 4; ++n) {
        long col = bn + wc + n * 16 + cc;
        float bv = bias[col];
        #pragma unroll
        for (int m = 0; m < 4; ++m) {
            #pragma unroll
            for (int r = 0; r < 4; ++r) {
                long row = bm + wr + m * 16 + r0 + r;
                float v = acc[m][n][r] + bv;
                v += R[row * N + col];
                ((float*)Cout)[row * N + col] = v;
            }
        }
    }
}

// ---------------- 256^2 8-phase bf16 MFMA GEMM ----------------
// BM=BN=256, BK=64, 512 thr (8 waves 2Mx4N), per-wave 128x64 out.
// LDS 128KB dynamic: A ring 2par x 2half x (128x64), B same at +64KB.
// EPI: 2 = bf16 gelu(x+bias); 3 = qkv scatter to qB|kB|vT
#define STG_A(KS, H) do { \
    const unsigned short* g_ = A + (long)(bm + (H) * 128 + srow) * K + (KS) * 64 + stgch; \
    unsigned short* s_ = LDS + (((KS) & 1) * 2 + (H)) * 8192 + (w * 8) * 64; \
    gl_lds16(g_, s_); gl_lds16(g_ + 64L * K, s_ + 4096); \
} while (0)
#define STG_B(KS, H) do { \
    const unsigned short* g_ = BT + (long)(bn + (H) * 128 + srow) * K + (KS) * 64 + stgch; \
    unsigned short* s_ = LDS + 32768 + (((KS) & 1) * 2 + (H)) * 8192 + (w * 8) * 64; \
    gl_lds16(g_, s_); gl_lds16(g_ + 64L * K, s_ + 4096); \
} while (0)
#define MM2(M_, x0, x1) do { \
    acc[M_][0] = __builtin_amdgcn_mfma_f32_16x16x32_bf16(x0, bfr[0], acc[M_][0], 0, 0, 0); \
    acc[M_][0] = __builtin_amdgcn_mfma_f32_16x16x32_bf16(x1, bfr[1], acc[M_][0], 0, 0, 0); \
    acc[M_][1] = __builtin_amdgcn_mfma_f32_16x16x32_bf16(x0, bfr[2], acc[M_][1], 0, 0, 0); \
    acc[M_][1] = __builtin_amdgcn_mfma_f32_16x16x32_bf16(x1, bfr[3], acc[M_][1], 0, 0, 0); \
    acc[M_][2] = __builtin_amdgcn_mfma_f32_16x16x32_bf16(x0, bfr[4], acc[M_][2], 0, 0, 0); \
    acc[M_][2] = __builtin_amdgcn_mfma_f32_16x16x32_bf16(x1, bfr[5], acc[M_][2], 0, 0, 0); \
    acc[M_][3] = __builtin_amdgcn_mfma_f32_16x16x32_bf16(x0, bfr[6], acc[M_][3], 0, 0, 0); \
    acc[M_][3] = __builtin_amdgcn_mfma_f32_16x16x32_bf16(x1, bfr[7], acc[M_][3], 0, 0, 0); \
} while (0)
#define PHASE(Q, SPAR, STAGE_STMT, TAIL_STMT) do { \
    bf16x8 a00, a01, a10, a11; \
    if (((Q) & 3) == 0) { \
        const unsigned short* Bb_ = lBp[SPAR] + ((wc & 1) * 64 + fr) * 64; \
        bfr[0] = *(const bf16x8*)(Bb_ + rd0);        bfr[1] = *(const bf16x8*)(Bb_ + rd1); \
        bfr[2] = *(const bf16x8*)(Bb_ + 1024 + rd0); bfr[3] = *(const bf16x8*)(Bb_ + 1024 + rd1); \
        bfr[4] = *(const bf16x8*)(Bb_ + 2048 + rd0); bfr[5] = *(const bf16x8*)(Bb_ + 2048 + rd1); \
        bfr[6] = *(const bf16x8*)(Bb_ + 3072 + rd0); bfr[7] = *(const bf16x8*)(Bb_ + 3072 + rd1); \
    } \
    { const unsigned short* Ab_ = lAp[SPAR] + fr * 64; \
      a00 = *(const bf16x8*)(Ab_ + (((Q) & 3) * 2) * 1024 + rd0); \
      a01 = *(const bf16x8*)(Ab_ + (((Q) & 3) * 2) * 1024 + rd1); \
      a10 = *(const bf16x8*)(Ab_ + (((Q) & 3) * 2 + 1) * 1024 + rd0); \
      a11 = *(const bf16x8*)(Ab_ + (((Q) & 3) * 2 + 1) * 1024 + rd1); } \
    STAGE_STMT; \
    __builtin_amdgcn_s_barrier(); \
    asm volatile("s_waitcnt lgkmcnt(0)" ::: "memory"); \
    __builtin_amdgcn_sched_barrier(0); \
    __builtin_amdgcn_s_setprio(1); \
    MM2(((Q) & 3) * 2, a00, a01); \
    MM2(((Q) & 3) * 2 + 1, a10, a11); \
    __builtin_amdgcn_s_setprio(0); \
    TAIL_STMT; \
    __builtin_amdgcn_s_barrier(); \
} while (0)

template<int EPI>
__global__ __launch_bounds__(512, 1)
void mm_mfma256(const unsigned short* __restrict__ A,
                const unsigned short* __restrict__ BT,
                const float* __restrict__ bias,
                void* __restrict__ Cout, int M, int N, int K, int nbx) {
    extern __shared__ unsigned short LDS[];
    const int tid = threadIdx.x;
    const int w = tid >> 6, lane = tid & 63;
    const int wr = w >> 2, wc = w & 3;
    const int nwg = gridDim.x, bid = blockIdx.x;
    const int swz = (bid & 7) * (nwg >> 3) + (bid >> 3);
    const int bm = (swz / nbx) * 256, bn = (swz % nbx) * 256;

    f32x4 acc[8][4];
    #pragma unroll
    for (int m = 0; m < 8; ++m)
        #pragma unroll
        for (int n = 0; n < 4; ++n)
            acc[m][n] = (f32x4){0.f, 0.f, 0.f, 0.f};

    const int fr = lane & 15, kg = lane >> 4;
    const int rd0 = 8 * (kg ^ (lane & 7)), rd1 = 8 * ((kg + 4) ^ (lane & 7));
    const int stgch = 8 * ((lane & 7) ^ (lane >> 3));
    const int srow = w * 8 + (lane >> 3);
    unsigned short* const lAp[2] = { LDS + wr * 8192, LDS + (2 + wr) * 8192 };
    unsigned short* const lBp[2] = { LDS + 32768 + (wc >> 1) * 8192,
                                     LDS + 32768 + (2 + (wc >> 1)) * 8192 };
    bf16x8 bfr[8];

    // prologue: stage B(0), A(0), B(1)
    STG_B(0, 0); STG_B(0, 1); STG_A(0, 0); STG_A(0, 1); STG_B(1, 0); STG_B(1, 1);
    asm volatile("s_waitcnt vmcnt(4)" ::: "memory");
    __builtin_amdgcn_sched_barrier(0);
    __builtin_amdgcn_s_barrier();

    const int T = K >> 7;   // iterations of 2 K-steps
    for (int t = 0; t < T; ++t) {
        const int s = 2 * t;
        const bool nl = (t < T - 1);
        PHASE(0, 0, STG_A(s + 1, 0), );
        PHASE(1, 0, STG_A(s + 1, 1), );
        PHASE(2, 0, if (nl) STG_B(s + 2, 0), );
        PHASE(3, 0, if (nl) STG_B(s + 2, 1),
              if (nl) { asm volatile("s_waitcnt vmcnt(4)" ::: "memory"); } else { asm volatile("s_waitcnt vmcnt(0)" ::: "memory"); } __builtin_amdgcn_sched_barrier(0); );
        PHASE(4, 1, if (nl) STG_A(s + 2, 0), );
        PHASE(5, 1, if (nl) STG_A(s + 2, 1), );
        PHASE(6, 1, if (nl) STG_B(s + 3, 0), );
        PHASE(7, 1, if (nl) STG_B(s + 3, 1),
              if (nl) { asm volatile("s_waitcnt vmcnt(4)" ::: "memory"); __builtin_amdgcn_sched_barrier(0); } );
    }

    // epilogue
    const int r0 = (lane >> 4) * 4;
    #pragma unroll
    for (int n = 0; n < 4; ++n) {
        int colb = bn + wc * 64 + n * 16;
        float bv = bias[colb + fr];
        #pragma unroll
        for (int m = 0; m < 8; ++m) {
            int rowb = bm + wr * 128 + m * 16 + r0;
            if (EPI == 3) {
                unsigned short* qkvB = (unsigned short*)Cout;
                int which = colb >> 10, hh = (colb & 1023) >> 6, dbase = colb & 63;
                int b_ = rowb >> 11, s_ = rowb & 2047;
                long bh2 = b_ * 16 + hh;
                float v[4];
                #pragma unroll
                for (int r = 0; r < 4; ++r) v[r] = acc[m][n][r] + bv;
                if (which == 2) {
                    ushort4v pk;
                    #pragma unroll
                    for (int r = 0; r < 4; ++r) pk[r] = f2bs(v[r]);
                    *(ushort4v*)&qkvB[8388608L + (bh2 * 64 + dbase + fr) * 2048 + s_] = pk;
                } else {
                    unsigned short* dst = qkvB + (long)which * 4194304L +
                                          (bh2 * 2048 + s_) * 64 + dbase + fr;
                    #pragma unroll
                    for (int r = 0; r < 4; ++r) dst[r * 64] = f2bs(v[r]);
                }
            } else {
                #pragma unroll
                for (int r = 0; r < 4; ++r) {
                    long row = rowb + r, col = colb + fr;
                    float v = acc[m][n][r] + bv;
                    v = 0.5f * v * (1.0f + erff(v * 0.70710678118f));
                    ((__hip_bfloat16*)Cout)[row * N + col] = __float2bfloat16(v);
                }
            }
        }
    }
}

// ---------------- MFMA flash attention ----------------
__global__ __launch_bounds__(256)
void attn_mfma(const unsigned short* __restrict__ qB,
               const unsigned short* __restrict__ kB,
               const unsigned short* __restrict__ vT,
               __hip_bfloat16* __restrict__ z) {
    const int bh = blockIdx.x;
    const int qb = blockIdx.y * 64;
    const int tid = threadIdx.x, w = tid >> 6, lane = tid & 63;
    const int arow = lane & 15, kg = lane >> 4;
    __shared__ unsigned short Ks[64 * 64];
    __shared__ unsigned short Vs[64 * 64];
    __shared__ unsigned short Ps[4][16 * 64];

    const long kvbase = (long)bh * (2048 * 64);

    bf16x8 qa[2];
    {
        const unsigned short* q0 = qB + kvbase + (long)(qb + w * 16 + arow) * 64 + kg * 8;
        qa[0] = *(const bf16x8*)(q0);
        qa[1] = *(const bf16x8*)(q0 + 32);
    }

    f32x4 po[4];
    float mrow[4], lrow[4];
    #pragma unroll
    for (int i = 0; i < 4; ++i) {
        po[i] = (f32x4){0.f, 0.f, 0.f, 0.f};
        mrow[i] = -1e30f; lrow[i] = 0.f;
    }

    const int srow = lane >> 3;
    const int schunk = (lane & 7) ^ srow;
    const int cmax = qb >> 6;

    for (int c = 0; c <= cmax; ++c) {
        {
            const unsigned short* ks0 = kB + kvbase + (long)(c * 64 + w * 16 + srow) * 64 + schunk * 8;
            const unsigned short* vs0 = vT + kvbase + (long)(w * 16 + srow) * 2048 + c * 64 + schunk * 8;
            gl_lds16(ks0,            &Ks[(w * 16) * 64]);
            gl_lds16(ks0 + 8 * 64,   &Ks[(w * 16 + 8) * 64]);
            gl_lds16(vs0,            &Vs[(w * 16) * 64]);
            gl_lds16(vs0 + 8 * 2048, &Vs[(w * 16 + 8) * 64]);
        }
        __syncthreads();

        f32x4 s[4];
        #pragma unroll
        for (int n = 0; n < 4; ++n) {
            s[n] = (f32x4){0.f, 0.f, 0.f, 0.f};
            int row = n * 16 + arow, sw = row & 7;
            bf16x8 kb0 = *(const bf16x8*)&Ks[row * 64 + (kg ^ sw) * 8];
            bf16x8 kb1 = *(const bf16x8*)&Ks[row * 64 + ((4 + kg) ^ sw) * 8];
            s[n] = __builtin_amdgcn_mfma_f32_16x16x32_bf16(qa[0], kb0, s[n], 0, 0, 0);
            s[n] = __builtin_amdgcn_mfma_f32_16x16x32_bf16(qa[1], kb1, s[n], 0, 0, 0);
        }

        const bool diag = (c == cmax);
        #pragma unroll
        for (int n = 0; n < 4; ++n)
            #pragma unroll
            for (int r = 0; r < 4; ++r) {
                float v = s[n][r] * 0.125f;
                if (diag) {
                    int key = c * 64 + n * 16 + arow;
                    int qrow = qb + w * 16 + kg * 4 + r;
                    if (key > qrow) v = -1e30f;
                }
                s[n][r] = v;
            }

        #pragma unroll
        for (int r = 0; r < 4; ++r) {
            float rm = fmaxf(fmaxf(s[0][r], s[1][r]), fmaxf(s[2][r], s[3][r]));
            #pragma unroll
            for (int off = 1; off < 16; off <<= 1)
                rm = fmaxf(rm, __shfl_xor(rm, off));
            float mnew = fmaxf(mrow[r], rm);
            float esc = expf(mrow[r] - mnew);
            float rs = 0.f;
            #pragma unroll
            for (int n = 0; n < 4; ++n) {
                float p = expf(s[n][r] - mnew);
                s[n][r] = p;
                rs += p;
            }
            #pragma unroll
            for (int off = 1; off < 16; off <<= 1)
                rs += __shfl_xor(rs, off);
            lrow[r] = lrow[r] * esc + rs;
            #pragma unroll
            for (int dt = 0; dt < 4; ++dt) po[dt][r] *= esc;
            mrow[r] = mnew;
        }

        #pragma unroll
        for (int n = 0; n < 4; ++n) {
            int col = n * 16 + arow;
            int chunk = col >> 3, cw = col & 7;
            #pragma unroll
            for (int r = 0; r < 4; ++r) {
                int row = kg * 4 + r;
                Ps[w][row * 64 + ((chunk ^ (row & 7)) * 8 + cw)] = f2bs(s[n][r]);
            }
        }

        bf16x8 pa[2];
        #pragma unroll
        for (int ks = 0; ks < 2; ++ks)
            pa[ks] = *(const bf16x8*)&Ps[w][arow * 64 + (((ks * 4 + kg) ^ (arow & 7)) * 8)];
        #pragma unroll
        for (int dt = 0; dt < 4; ++dt) {
            int vrow = dt * 16 + arow, sw = vrow & 7;
            bf16x8 vb0 = *(const bf16x8*)&Vs[vrow * 64 + ((kg ^ sw) * 8)];
            bf16x8 vb1 = *(const bf16x8*)&Vs[vrow * 64 + (((4 + kg) ^ sw) * 8)];
            po[dt] = __builtin_amdgcn_mfma_f32_16x16x32_bf16(pa[0], vb0, po[dt], 0, 0, 0);
            po[dt] = __builtin_amdgcn_mfma_f32_16x16x32_bf16(pa[1], vb1, po[dt], 0, 0, 0);
        }
        __syncthreads();
    }

    const int b_ = bh >> 4, hofs = (bh & 15) * 64;
    #pragma unroll
    for (int dt = 0; dt < 4; ++dt)
        #pragma unroll
        for (int r = 0; r < 4; ++r) {
            long row = (long)b_ * 2048 + qb + w * 16 + kg * 4 + r;
            z[row * 1024 + hofs + dt * 16 + arow] = __float2bfloat16(po[dt][r] / lrow[r]);
        }
}

// ---------------- head ----------------
__global__ void head_kernel(const float* __restrict__ hl, const float* __restrict__ W,
                            float* __restrict__ out) {
    __shared__ float hs[2 * DMODEL];
    int tid = threadIdx.x;
    #pragma unroll
    for (int i = 0; i < 8; ++i) hs[tid + i * 256] = hl[tid + i * 256];
    __syncthreads();
    int v = blockIdx.x * 256 + tid;
    if (v >= VOCAB) return;
    float a0 = 0.f, a1 = 0.f;
    for (int d = 0; d < DMODEL; ++d) {
        float wv = W[(long)d * VOCAB + v];
        a0 += hs[d] * wv;
        a1 += hs[DMODEL + d] * wv;
    }
    out[v] = a0;
    out[VOCAB + v] = a1;
}

extern "C" void kernel_launch(void* const* d_in, const int* in_sizes, int n_in,
                              void* d_out, int out_size, void* d_ws, size_t ws_size,
                              hipStream_t stream) {
    const int*   x      = (const int*)  d_in[0];
    const float* wte    = (const float*)d_in[1];
    const float* wpe    = (const float*)d_in[2];
    const float* ln1_g  = (const float*)d_in[3];
    const float* ln1_b  = (const float*)d_in[4];
    const float* w_qkv  = (const float*)d_in[5];
    const float* b_qkv  = (const float*)d_in[6];
    const float* w_proj = (const float*)d_in[7];
    const float* b_proj = (const float*)d_in[8];
    const float* ln2_g  = (const float*)d_in[9];
    const float* ln2_b  = (const float*)d_in[10];
    const float* w_fc   = (const float*)d_in[11];
    const float* b_fc   = (const float*)d_in[12];
    const float* w_cp   = (const float*)d_in[13];
    const float* b_cp   = (const float*)d_in[14];
    const float* lnf_g  = (const float*)d_in[15];
    const float* lnf_b  = (const float*)d_in[16];
    const float* w_head = (const float*)d_in[17];
    float* out = (float*)d_out;

    char* ws = (char*)d_ws;
    float*          h     = (float*)ws;                             // 16 MB
    unsigned short* qkvB  = (unsigned short*)(ws + (16L << 20));    // 24 MB
    __hip_bfloat16* y_bf  = (__hip_bfloat16*)(ws + (40L << 20));    // 8 MB
    __hip_bfloat16* z_bf  = (__hip_bfloat16*)(ws + (48L << 20));    // 8 MB
    __hip_bfloat16* fc_bf = (__hip_bfloat16*)(ws + (56L << 20));    // 32 MB
    float*          hl    = (float*)(ws + (88L << 20));             // 8 KB
    unsigned short* wsT   = (unsigned short*)(ws + (96L << 20));    // 202 MB arena

    convT_all<<<98304, 256, 0, stream>>>(w_qkv, w_proj, w_fc, w_cp, wsT);
    embed_kernel<<<NTOK, 256, 0, stream>>>(x, wte, wpe, h);

    for (int l = 0; l < NLAYER; ++l) {
        unsigned short* wl = wsT + l * LWOFF;
        ln_kernel<__hip_bfloat16><<<NTOK, 256, 0, stream>>>(
            h, y_bf, ln1_g + l * DMODEL, ln1_b + l * DMODEL, DMODEL);

        mm_mfma256<3><<<192, 512, 131072, stream>>>(
            (const unsigned short*)y_bf, wl, b_qkv + l * 3072, qkvB,
            NTOK, 3072, 1024, 12);

        attn_mfma<<<dim3(BATCH * NHEAD, SEQ / 64), 256, 0, stream>>>(
            qkvB, qkvB + 4194304L, qkvB + 8388608L, z_bf);

        mm_mfma<1><<<dim3(8, 32), 256, 0, stream>>>(
            (const unsigned short*)z_bf, wl + 3145728, b_proj + l * DMODEL, h, h,
            NTOK, 1024, 1024);

        ln_kernel<__hip_bfloat16><<<NTOK, 256, 0, stream>>>(
            h, y_bf, ln2_g + l * DMODEL, ln2_b + l * DMODEL, DMODEL);

        mm_mfma256<2><<<256, 512, 131072, stream>>>(
            (const unsigned short*)y_bf, wl + 4194304, b_fc + l * 4096, fc_bf,
            NTOK, 4096, 1024, 16);

        mm_mfma<1><<<dim3(8, 32), 256, 0, stream>>>(
            (const unsigned short*)fc_bf, wl + 8388608, b_cp + l * DMODEL, h, h,
            NTOK, 1024, 4096);
    }

    ln_kernel<float><<<BATCH, 256, 0, stream>>>(h + (long)(SEQ - 1) * DMODEL, hl,
                                                lnf_g, lnf_b, (long)SEQ * DMODEL);
    head_kernel<<<(VOCAB + 255) / 256, 256, 0, stream>>>(hl, w_head, out);
}